// Round 1
// baseline (1490.982 us; speedup 1.0000x reference)
//
#include <hip/hip_runtime.h>
#include <math.h>

#define BB 32
#define TT 64
#define NNODES 256
#define FDIM 64
#define SLICE (NNODES*FDIM)          // 16384 floats per (b,t) slice
#define NTOT (BB*TT*NNODES*FDIM)     // 33554432
#define RANK0 838860u                // ascending order-statistic index: T*N*F - k - 1, k=209715

// ---------------- weight combine: 7 effective taps (-3..+3) ----------------
__global__ __launch_bounds__(256) void combine_w(
    const float* __restrict__ Wc1, const float* __restrict__ bc1,
    const float* __restrict__ Wc2, const float* __restrict__ bc2,
    const float* __restrict__ Wc3, const float* __restrict__ bc3,
    float* __restrict__ Wcomb, float* __restrict__ bcomb)
{
  const int FF2 = FDIM*FDIM;
  int gid = blockIdx.x*256 + threadIdx.x;
  if (gid < 7*FF2) {
    int j = gid / FF2, r = gid % FF2;
    float v;
    switch (j) {
      case 0: v = Wc3[r]; break;                                   // offset -3
      case 1: v = Wc2[r]; break;                                   // offset -2
      case 2: v = Wc1[r]; break;                                   // offset -1
      case 3: v = Wc1[FF2+r] + Wc2[FF2+r] + Wc3[FF2+r]; break;     // offset  0
      case 4: v = Wc1[2*FF2+r]; break;                             // offset +1
      case 5: v = Wc2[2*FF2+r]; break;                             // offset +2
      default: v = Wc3[2*FF2+r]; break;                            // offset +3
    }
    Wcomb[gid] = v;
  }
  if (gid < FDIM) bcomb[gid] = bc1[gid] + bc2[gid] + bc3[gid];
}

// ---------------- dilated conv block + residual, per (b,n) slice ----------------
__global__ __launch_bounds__(256,4) void conv_kernel(
    const float* __restrict__ x, const float* __restrict__ Wcomb,
    const float* __restrict__ bcomb, float* __restrict__ x1)
{
  __shared__ float xs[64*72];        // [f][t+4], t in [-4,68), zero-padded
  const int bn = blockIdx.x; const int b = bn >> 8; const int n = bn & 255;
  const int tid = threadIdx.x;
#pragma unroll
  for (int k=0;k<18;k++) xs[k*256+tid] = 0.f;
  __syncthreads();
  const float* xbase = x + ((size_t)b*TT)*SLICE + n*FDIM;
#pragma unroll
  for (int it=0; it<4; it++) {
    int flat4 = it*256 + tid;
    int t = flat4 >> 4, f4 = (flat4 & 15) << 2;
    float4 v = *(const float4*)(xbase + (size_t)t*SLICE + f4);
    xs[(f4+0)*72 + t+4] = v.x;
    xs[(f4+1)*72 + t+4] = v.y;
    xs[(f4+2)*72 + t+4] = v.z;
    xs[(f4+3)*72 + t+4] = v.w;
  }
  __syncthreads();
  const int o = tid & 63;            // lane -> output feature
  const int tb = (tid >> 6) << 4;    // wave -> 16-step t range (wave-uniform)
  float acc[16];
  const float bco = bcomb[o];
#pragma unroll
  for (int k=0;k<16;k++) acc[k] = bco;
  for (int i=0;i<FDIM;i++) {
    float xr[24];
#pragma unroll
    for (int q=0;q<6;q++) {          // aligned b128 broadcast reads (tb wave-uniform)
      float4 v = *(const float4*)&xs[i*72 + tb + q*4];
      xr[q*4+0]=v.x; xr[q*4+1]=v.y; xr[q*4+2]=v.z; xr[q*4+3]=v.w;
    }
#pragma unroll
    for (int j=0;j<7;j++) {
      float w = Wcomb[(j*FDIM+i)*FDIM + o];   // coalesced, L2-hot
#pragma unroll
      for (int k=0;k<16;k++) acc[k] = fmaf(xr[k+j+1], w, acc[k]);
    }
  }
  float* obase = x1 + ((size_t)b*TT)*SLICE + n*FDIM + o;
#pragma unroll
  for (int k=0;k<16;k++) {
    int t = tb + k;
    float c = acc[k];
    float outv = xs[o*72 + t+4] + (c > 0.f ? c : 0.f);  // residual + relu
    obase[(size_t)t*SLICE] = outv;
  }
}

// ---------------- attention (diag softmax) + dense + inf-norm, per (b,t) ----------------
__global__ __launch_bounds__(256,2) void attn_kernel(
    const float* __restrict__ x1,
    const float* __restrict__ Wq, const float* __restrict__ bq,
    const float* __restrict__ Wk, const float* __restrict__ bk,
    const float* __restrict__ Wv, const float* __restrict__ bv,
    const float* __restrict__ Wd, const float* __restrict__ bd,
    float* __restrict__ vout)
{
  __shared__ float ks[NNODES*68];    // staging for x slice, then K rows, then v rows
  const int bt = blockIdx.x;
  const int tid = threadIdx.x;       // thread == node n
  const float4* xb4 = (const float4*)(x1 + (size_t)bt*SLICE);
#pragma unroll
  for (int it=0; it<16; it++) {      // coalesced stage-in
    int flat4 = it*256 + tid;
    int n = flat4 >> 4, f4 = (flat4 & 15) << 2;
    *(float4*)&ks[n*68 + f4] = xb4[flat4];
  }
  __syncthreads();
  float xr[64];                      // own x row in registers
#pragma unroll
  for (int q=0;q<16;q++) {
    float4 v = *(const float4*)&ks[tid*68 + q*4];
    xr[q*4+0]=v.x; xr[q*4+1]=v.y; xr[q*4+2]=v.z; xr[q*4+3]=v.w;
  }
  // K row -> overwrite own LDS row (own-row only: no sync needed here)
  {
    float a[64];
#pragma unroll
    for (int o=0;o<64;o++) a[o]=0.f;
    for (int i=0;i<64;i++) {
      float xv = xr[i];
#pragma unroll
      for (int o=0;o<64;o++) a[o] = fmaf(xv, Wk[i*64+o], a[o]);
    }
#pragma unroll
    for (int q=0;q<16;q++) {
      float4 w;
      w.x = a[q*4+0]+bk[q*4+0]; w.y = a[q*4+1]+bk[q*4+1];
      w.z = a[q*4+2]+bk[q*4+2]; w.w = a[q*4+3]+bk[q*4+3];
      *(float4*)&ks[tid*68 + q*4] = w;
    }
  }
  // Q row in registers
  float qr[64];
#pragma unroll
  for (int o=0;o<64;o++) qr[o]=0.f;
  for (int i=0;i<64;i++) {
    float xv = xr[i];
#pragma unroll
    for (int o=0;o<64;o++) qr[o] = fmaf(xv, Wq[i*64+o], qr[o]);
  }
#pragma unroll
  for (int o=0;o<64;o++) qr[o] += bq[o];
  __syncthreads();                   // all K rows visible
  // scores row + online softmax stats (only diag of A is needed)
  float M = -3.402823466e38f, S = 0.f, diag = 0.f;
  for (int m=0;m<NNODES;m++) {
    float s = 0.f;
#pragma unroll
    for (int q=0;q<16;q++) {         // uniform-address b128 broadcast
      float4 kv = *(const float4*)&ks[m*68 + q*4];
      s = fmaf(qr[q*4+0], kv.x, s);
      s = fmaf(qr[q*4+1], kv.y, s);
      s = fmaf(qr[q*4+2], kv.z, s);
      s = fmaf(qr[q*4+3], kv.w, s);
    }
    s *= 0.125f;                     // / sqrt(64), exact
    if (m == tid) diag = s;
    if (s > M) { S = S * expf(M - s) + 1.f; M = s; }
    else       { S += expf(s - M); }
  }
  const float ann = expf(diag - M) / S;
  // V row -> g -> relu -> residual
  float o1[64];
#pragma unroll
  for (int o=0;o<64;o++) o1[o]=0.f;
  for (int i=0;i<64;i++) {
    float xv = xr[i];
#pragma unroll
    for (int o=0;o<64;o++) o1[o] = fmaf(xv, Wv[i*64+o], o1[o]);
  }
#pragma unroll
  for (int o=0;o<64;o++) {
    float g = ann * (o1[o] + bv[o]);
    o1[o] = xr[o] + (g > 0.f ? g : 0.f);
  }
  // dense projection
  float dd[64];
#pragma unroll
  for (int o=0;o<64;o++) dd[o]=0.f;
  for (int i=0;i<64;i++) {
    float ov = o1[i];
#pragma unroll
    for (int o=0;o<64;o++) dd[o] = fmaf(ov, Wd[i*64+o], dd[o]);
  }
  float nrm = 0.f;
#pragma unroll
  for (int o=0;o<64;o++) { dd[o] += bd[o]; nrm = fmaxf(nrm, fabsf(dd[o])); }
  __syncthreads();                   // all score reads of ks done before overwrite
#pragma unroll
  for (int q=0;q<16;q++) {
    float4 w;
    w.x = 0.5f*(dd[q*4+0]/nrm + 1.f);
    w.y = 0.5f*(dd[q*4+1]/nrm + 1.f);
    w.z = 0.5f*(dd[q*4+2]/nrm + 1.f);
    w.w = 0.5f*(dd[q*4+3]/nrm + 1.f);
    *(float4*)&ks[tid*68 + q*4] = w;
  }
  __syncthreads();
  float4* ob4 = (float4*)(vout + (size_t)bt*SLICE);
#pragma unroll
  for (int it=0;it<16;it++) {        // coalesced stage-out
    int flat4 = it*256 + tid;
    int n = flat4 >> 4, f4 = (flat4 & 15) << 2;
    ob4[flat4] = *(const float4*)&ks[n*68 + f4];
  }
}

// ---------------- radix-select histograms (values are non-negative floats) ----------------
template<int LEVEL>
__global__ __launch_bounds__(256) void hist_kernel(
    const float* __restrict__ v, unsigned* __restrict__ ghist,
    const unsigned* __restrict__ pfx)
{
  __shared__ unsigned h[4096];
  const int batch = blockIdx.x >> 5, chunk = blockIdx.x & 31;
  const int tid = threadIdx.x;
#pragma unroll
  for (int k=0;k<16;k++) h[k*256+tid] = 0u;
  __syncthreads();
  const unsigned p = pfx ? pfx[batch] : 0u;
  const float4* vb = (const float4*)(v + (size_t)batch*(TT*SLICE)) + chunk*8192 + tid;
  for (int k=0;k<32;k++) {
    float4 q = vb[k*256];
    float e[4] = {q.x,q.y,q.z,q.w};
#pragma unroll
    for (int j=0;j<4;j++) {
      unsigned u = __float_as_uint(e[j]);
      if (LEVEL==1) atomicAdd(&h[u>>20], 1u);
      else if ((u>>20)==p) atomicAdd(&h[(u>>8)&0xFFFu], 1u);
    }
  }
  __syncthreads();
  unsigned* gh = ghist + batch*4096;
#pragma unroll
  for (int k=0;k<16;k++) { unsigned c = h[k*256+tid]; if (c) atomicAdd(&gh[k*256+tid], c); }
}

__global__ __launch_bounds__(256) void hist8_kernel(
    const float* __restrict__ v, unsigned* __restrict__ ghist,
    const unsigned* __restrict__ pfx)
{
  __shared__ unsigned h[256];
  const int batch = blockIdx.x >> 5, chunk = blockIdx.x & 31;
  const int tid = threadIdx.x;
  h[tid] = 0u;
  __syncthreads();
  const unsigned p = pfx[batch];
  const float4* vb = (const float4*)(v + (size_t)batch*(TT*SLICE)) + chunk*8192 + tid;
  for (int k=0;k<32;k++) {
    float4 q = vb[k*256];
    float e[4] = {q.x,q.y,q.z,q.w};
#pragma unroll
    for (int j=0;j<4;j++) {
      unsigned u = __float_as_uint(e[j]);
      if ((u>>8)==p) atomicAdd(&h[u & 255u], 1u);
    }
  }
  __syncthreads();
  unsigned c = h[tid];
  if (c) atomicAdd(&ghist[batch*256+tid], c);
}

// ---------------- find bin containing the rank (block scan per batch) ----------------
template<int PER>
__global__ __launch_bounds__(256) void find_kernel(
    const unsigned* __restrict__ hist,
    const unsigned* __restrict__ rank_in, const unsigned* __restrict__ pfx_in,
    int pfx_shift, unsigned* __restrict__ pfx_out, unsigned* __restrict__ rank_out,
    float* __restrict__ mu, int final_level)
{
  __shared__ unsigned csum[256];
  const int batch = blockIdx.x;
  const int tid = threadIdx.x;
  const unsigned* hb = hist + batch*(PER*256);
  unsigned loc[PER];
  unsigned s = 0;
#pragma unroll
  for (int q=0;q<PER;q++) { loc[q] = hb[tid*PER+q]; s += loc[q]; }
  csum[tid] = s;
  __syncthreads();
  for (int off=1; off<256; off<<=1) {   // inclusive Hillis-Steele scan
    unsigned vv = csum[tid];
    unsigned ad = (tid >= off) ? csum[tid-off] : 0u;
    __syncthreads();
    csum[tid] = vv + ad;
    __syncthreads();
  }
  const unsigned rank = rank_in ? rank_in[batch] : RANK0;
  const unsigned excl = csum[tid] - s;
  if (rank >= excl && rank < excl + s) {
    unsigned r = rank - excl;
    int bin = 0;
#pragma unroll
    for (int q=0;q<PER;q++) {
      if (r < loc[q]) { bin = tid*PER + q; break; }
      r -= loc[q];
    }
    unsigned pf = pfx_in ? pfx_in[batch] : 0u;
    unsigned np = (pf << pfx_shift) | (unsigned)bin;
    if (final_level) { mu[batch] = __uint_as_float(np); }
    else { pfx_out[batch] = np; rank_out[batch] = r; }
  }
}

// ---------------- sigmoid + STE mask + predictor, per (b,t) ----------------
__global__ __launch_bounds__(256,2) void final_kernel(
    const float* __restrict__ v, const float* __restrict__ mu,
    const float* __restrict__ Wp, const float* __restrict__ bp,
    float* __restrict__ pred, float* __restrict__ mask)
{
  __shared__ float sl[NNODES*68];
  const int bt = blockIdx.x;
  const int b = bt >> 6;
  const int tid = threadIdx.x;
  const float4* vb4 = (const float4*)(v + (size_t)bt*SLICE);
#pragma unroll
  for (int it=0; it<16; it++) {
    int flat4 = it*256 + tid;
    int n = flat4 >> 4, f4 = (flat4 & 15) << 2;
    *(float4*)&sl[n*68 + f4] = vb4[flat4];
  }
  __syncthreads();
  const float muv = mu[b];
  float srow[64];                    // masked = s*mask row kept in registers
#pragma unroll
  for (int q=0;q<16;q++) {
    float4 vv = *(const float4*)&sl[tid*68 + q*4];
    float e0 = 1.f/(1.f + expf(-(vv.x - muv)));
    float e1 = 1.f/(1.f + expf(-(vv.y - muv)));
    float e2 = 1.f/(1.f + expf(-(vv.z - muv)));
    float e3 = 1.f/(1.f + expf(-(vv.w - muv)));
    float m0 = rintf(e0), m1 = rintf(e1), m2 = rintf(e2), m3 = rintf(e3);  // round half-even
    srow[q*4+0] = e0*m0; srow[q*4+1] = e1*m1; srow[q*4+2] = e2*m2; srow[q*4+3] = e3*m3;
    float4 w; w.x=m0; w.y=m1; w.z=m2; w.w=m3;
    *(float4*)&sl[tid*68 + q*4] = w;  // own row only: safe
  }
  __syncthreads();
  float4* mb4 = (float4*)(mask + (size_t)bt*SLICE);
#pragma unroll
  for (int it=0; it<16; it++) {
    int flat4 = it*256 + tid;
    int n = flat4 >> 4, f4 = (flat4 & 15) << 2;
    mb4[flat4] = *(const float4*)&sl[n*68 + f4];
  }
  // predictor row
  float acc[64];
#pragma unroll
  for (int o=0;o<64;o++) acc[o]=0.f;
  for (int i=0;i<64;i++) {
    float sv = srow[i];
#pragma unroll
    for (int o=0;o<64;o++) acc[o] = fmaf(sv, Wp[i*64+o], acc[o]);
  }
  __syncthreads();                   // mask stage-out finished reading sl
#pragma unroll
  for (int q=0;q<16;q++) {
    float4 w;
    w.x = acc[q*4+0]+bp[q*4+0]; w.y = acc[q*4+1]+bp[q*4+1];
    w.z = acc[q*4+2]+bp[q*4+2]; w.w = acc[q*4+3]+bp[q*4+3];
    *(float4*)&sl[tid*68 + q*4] = w;
  }
  __syncthreads();
  float4* pb4 = (float4*)(pred + (size_t)bt*SLICE);
#pragma unroll
  for (int it=0; it<16; it++) {
    int flat4 = it*256 + tid;
    int n = flat4 >> 4, f4 = (flat4 & 15) << 2;
    pb4[flat4] = *(const float4*)&sl[n*68 + f4];
  }
}

extern "C" void kernel_launch(void* const* d_in, const int* in_sizes, int n_in,
                              void* d_out, int out_size, void* d_ws, size_t ws_size,
                              hipStream_t stream) {
  const float* x   = (const float*)d_in[0];
  const float* Wc1 = (const float*)d_in[1];  const float* bc1 = (const float*)d_in[2];
  const float* Wc2 = (const float*)d_in[3];  const float* bc2 = (const float*)d_in[4];
  const float* Wc3 = (const float*)d_in[5];  const float* bc3 = (const float*)d_in[6];
  const float* Wq  = (const float*)d_in[7];  const float* bq  = (const float*)d_in[8];
  const float* Wk  = (const float*)d_in[9];  const float* bk  = (const float*)d_in[10];
  const float* Wv  = (const float*)d_in[11]; const float* bv  = (const float*)d_in[12];
  const float* Wd  = (const float*)d_in[13]; const float* bd  = (const float*)d_in[14];
  const float* Wp  = (const float*)d_in[15]; const float* bp  = (const float*)d_in[16];

  float* pred = (float*)d_out;       // also holds pre-sigmoid v, overwritten in place
  float* mask = pred + NTOT;         // also holds conv output x1, overwritten in place

  unsigned* hist1 = (unsigned*)d_ws;           // 32*4096
  unsigned* hist2 = hist1 + 32*4096;           // 32*4096
  unsigned* hist3 = hist2 + 32*4096;           // 32*256
  unsigned* pfx1  = hist3 + 32*256;
  unsigned* rank1 = pfx1 + 32;
  unsigned* pfx2  = rank1 + 32;
  unsigned* rank2 = pfx2 + 32;
  float*    muv   = (float*)(rank2 + 32);
  float*    Wcomb = muv + 32;                  // 7*64*64
  float*    bcomb = Wcomb + 7*64*64;           // 64

  hipMemsetAsync(d_ws, 0, (size_t)(32*4096*2 + 32*256)*sizeof(unsigned), stream);
  combine_w<<<112, 256, 0, stream>>>(Wc1,bc1,Wc2,bc2,Wc3,bc3,Wcomb,bcomb);
  conv_kernel<<<BB*NNODES, 256, 0, stream>>>(x, Wcomb, bcomb, mask /*x1*/);
  attn_kernel<<<BB*TT, 256, 0, stream>>>(mask /*x1*/, Wq,bq,Wk,bk,Wv,bv,Wd,bd, pred /*v*/);
  hist_kernel<1><<<1024, 256, 0, stream>>>(pred, hist1, nullptr);
  find_kernel<16><<<32, 256, 0, stream>>>(hist1, nullptr, nullptr, 0, pfx1, rank1, nullptr, 0);
  hist_kernel<2><<<1024, 256, 0, stream>>>(pred, hist2, pfx1);
  find_kernel<16><<<32, 256, 0, stream>>>(hist2, rank1, pfx1, 12, pfx2, rank2, nullptr, 0);
  hist8_kernel<<<1024, 256, 0, stream>>>(pred, hist3, pfx2);
  find_kernel<1><<<32, 256, 0, stream>>>(hist3, rank2, pfx2, 8, nullptr, nullptr, muv, 1);
  final_kernel<<<BB*TT, 256, 0, stream>>>(pred /*v*/, muv, Wp, bp, pred, mask);
}

// Round 2
// 1195.821 us; speedup vs baseline: 1.2468x; 1.2468x over previous
//
#include <hip/hip_runtime.h>
#include <math.h>

#define BB 32
#define TT 64
#define NNODES 256
#define FDIM 64
#define SLICE (NNODES*FDIM)          // 16384 floats per (b,t) slice
#define NTOT (BB*TT*NNODES*FDIM)     // 33554432
#define RANK0 838860u                // ascending order-statistic index: T*N*F - k - 1, k=209715

typedef float v2f __attribute__((ext_vector_type(2)));
__device__ __forceinline__ v2f pkfma(v2f a, v2f b, v2f c) {
#if __has_builtin(__builtin_elementwise_fma)
  return __builtin_elementwise_fma(a, b, c);   // -> v_pk_fma_f32
#else
  v2f r; r.x = fmaf(a.x,b.x,c.x); r.y = fmaf(a.y,b.y,c.y); return r;
#endif
}

// ---------------- weight combine: 7 effective taps (-3..+3) ----------------
__global__ __launch_bounds__(256) void combine_w(
    const float* __restrict__ Wc1, const float* __restrict__ bc1,
    const float* __restrict__ Wc2, const float* __restrict__ bc2,
    const float* __restrict__ Wc3, const float* __restrict__ bc3,
    float* __restrict__ Wcomb, float* __restrict__ bcomb)
{
  const int FF2 = FDIM*FDIM;
  int gid = blockIdx.x*256 + threadIdx.x;
  if (gid < 7*FF2) {
    int j = gid / FF2, r = gid % FF2;
    float v;
    switch (j) {
      case 0: v = Wc3[r]; break;                                   // offset -3
      case 1: v = Wc2[r]; break;                                   // offset -2
      case 2: v = Wc1[r]; break;                                   // offset -1
      case 3: v = Wc1[FF2+r] + Wc2[FF2+r] + Wc3[FF2+r]; break;     // offset  0
      case 4: v = Wc1[2*FF2+r]; break;                             // offset +1
      case 5: v = Wc2[2*FF2+r]; break;                             // offset +2
      default: v = Wc3[2*FF2+r]; break;                            // offset +3
    }
    Wcomb[gid] = v;
  }
  if (gid < FDIM) bcomb[gid] = bc1[gid] + bc2[gid] + bc3[gid];
}

// ---------------- fold Q/K projections: Wqk = Wq*Wk^T, zb = bq*Wk^T, wqbk = Wq*bk, bqbk ----------------
__global__ __launch_bounds__(256) void combine_qk(
    const float* __restrict__ Wq, const float* __restrict__ bq,
    const float* __restrict__ Wk, const float* __restrict__ bk,
    float* __restrict__ Wqk, float* __restrict__ zb,
    float* __restrict__ wqbk, float* __restrict__ bqbk)
{
  int gid = blockIdx.x*256 + threadIdx.x;
  if (gid < 4096) {
    int i = gid >> 6, j = gid & 63;
    float a = 0.f;
    for (int o=0;o<64;o++) a = fmaf(Wq[i*64+o], Wk[j*64+o], a);
    Wqk[i*64+j] = a;
  } else if (gid < 4160) {
    int j = gid - 4096;
    float a = 0.f;
    for (int o=0;o<64;o++) a = fmaf(bq[o], Wk[j*64+o], a);
    zb[j] = a;
  } else if (gid < 4224) {
    int i = gid - 4160;
    float a = 0.f;
    for (int o=0;o<64;o++) a = fmaf(Wq[i*64+o], bk[o], a);
    wqbk[i] = a;
  } else if (gid == 4224) {
    float a = 0.f;
    for (int o=0;o<64;o++) a = fmaf(bq[o], bk[o], a);
    bqbk[0] = a;
  }
}

// ---------------- dilated conv block + residual, per (b,n) slice ----------------
__global__ __launch_bounds__(256,4) void conv_kernel(
    const float* __restrict__ x, const float* __restrict__ Wcomb,
    const float* __restrict__ bcomb, float* __restrict__ x1)
{
  __shared__ float xs[64*72];        // [f][t+4], t in [-4,68), zero-padded
  const int bn = blockIdx.x; const int b = bn >> 8; const int n = bn & 255;
  const int tid = threadIdx.x;
#pragma unroll
  for (int k=0;k<18;k++) xs[k*256+tid] = 0.f;
  __syncthreads();
  const float* xbase = x + ((size_t)b*TT)*SLICE + n*FDIM;
#pragma unroll
  for (int it=0; it<4; it++) {
    int flat4 = it*256 + tid;
    int t = flat4 >> 4, f4 = (flat4 & 15) << 2;
    float4 v = *(const float4*)(xbase + (size_t)t*SLICE + f4);
    xs[(f4+0)*72 + t+4] = v.x;
    xs[(f4+1)*72 + t+4] = v.y;
    xs[(f4+2)*72 + t+4] = v.z;
    xs[(f4+3)*72 + t+4] = v.w;
  }
  __syncthreads();
  const int o = tid & 63;            // lane -> output feature
  const int tb = (tid >> 6) << 4;    // wave -> 16-step t range (wave-uniform)
  float acc[16];
  const float bco = bcomb[o];
#pragma unroll
  for (int k=0;k<16;k++) acc[k] = bco;
  for (int i=0;i<FDIM;i++) {
    float xr[24];
#pragma unroll
    for (int q=0;q<6;q++) {          // aligned b128 broadcast reads (tb wave-uniform)
      float4 v = *(const float4*)&xs[i*72 + tb + q*4];
      xr[q*4+0]=v.x; xr[q*4+1]=v.y; xr[q*4+2]=v.z; xr[q*4+3]=v.w;
    }
#pragma unroll
    for (int j=0;j<7;j++) {
      float w = Wcomb[(j*FDIM+i)*FDIM + o];   // coalesced, L2-hot
#pragma unroll
      for (int k=0;k<16;k++) acc[k] = fmaf(xr[k+j+1], w, acc[k]);
    }
  }
  float* obase = x1 + ((size_t)b*TT)*SLICE + n*FDIM + o;
#pragma unroll
  for (int k=0;k<16;k++) {
    int t = tb + k;
    float c = acc[k];
    float outv = xs[o*72 + t+4] + (c > 0.f ? c : 0.f);  // residual + relu
    obase[(size_t)t*SLICE] = outv;
  }
}

// ---------------- attention (diag softmax) + dense + inf-norm, per (b,t) ----------------
// Factored scores: s(n,m) = (z[n]·x[m] + d[n]) / 8, z = x·Wqk + zb, d = x·wqbk + bqbk.
// exp(diag - M)/sum(exp(s - M)) == exp(diag)/sum(exp(s)): M cancels exactly.
__global__ __launch_bounds__(256,2) void attn_kernel(
    const float* __restrict__ x1,
    const float* __restrict__ Wqk, const float* __restrict__ zb,
    const float* __restrict__ wqbk, const float* __restrict__ bqbk,
    const float* __restrict__ Wv, const float* __restrict__ bv,
    const float* __restrict__ Wd, const float* __restrict__ bd,
    float* __restrict__ vout)
{
  __shared__ float ks[NNODES*68];    // x slice (stride 68), later reused for output transpose
  const int bt = blockIdx.x;
  const int tid = threadIdx.x;       // thread == node n
  const float4* xb4 = (const float4*)(x1 + (size_t)bt*SLICE);
#pragma unroll
  for (int it=0; it<16; it++) {      // coalesced stage-in
    int flat4 = it*256 + tid;
    int n = flat4 >> 4, f4 = (flat4 & 15) << 2;
    *(float4*)&ks[n*68 + f4] = xb4[flat4];
  }
  __syncthreads();

  // z = x·Wqk + zb (packed), d = x·wqbk + bqbk
  v2f zp[32];
  float d = bqbk[0];
  {
    float xr[64];
#pragma unroll
    for (int q=0;q<16;q++) {
      float4 v = *(const float4*)&ks[tid*68 + q*4];
      xr[q*4+0]=v.x; xr[q*4+1]=v.y; xr[q*4+2]=v.z; xr[q*4+3]=v.w;
    }
#pragma unroll
    for (int j=0;j<32;j++) { v2f t; t.x = zb[2*j]; t.y = zb[2*j+1]; zp[j] = t; }
    for (int i=0;i<64;i++) {
      v2f xv; xv.x = xr[i]; xv.y = xr[i];
      const float4* wr = (const float4*)(Wqk + i*64);
#pragma unroll
      for (int q=0;q<16;q++) {
        float4 w4 = wr[q];
        v2f wlo; wlo.x=w4.x; wlo.y=w4.y;
        v2f whi; whi.x=w4.z; whi.y=w4.w;
        zp[2*q]   = pkfma(xv, wlo, zp[2*q]);
        zp[2*q+1] = pkfma(xv, whi, zp[2*q+1]);
      }
      d = fmaf(xr[i], wqbk[i], d);
    }
  }

  // scores row: online exp-sum (no max needed), diag capture
  float S0 = 0.f, S1 = 0.f, diag = 0.f;
  for (int m=0;m<NNODES;m+=2) {
    v2f a0={0.f,0.f}, a1={0.f,0.f}, b0={0.f,0.f}, b1={0.f,0.f};
#pragma unroll
    for (int q=0;q<16;q++) {
      float4 k0 = *(const float4*)&ks[m*68 + q*4];       // wave-uniform broadcast
      float4 k1 = *(const float4*)&ks[(m+1)*68 + q*4];
      v2f k0lo; k0lo.x=k0.x; k0lo.y=k0.y;
      v2f k0hi; k0hi.x=k0.z; k0hi.y=k0.w;
      v2f k1lo; k1lo.x=k1.x; k1lo.y=k1.y;
      v2f k1hi; k1hi.x=k1.z; k1hi.y=k1.w;
      a0 = pkfma(zp[2*q],   k0lo, a0);
      a1 = pkfma(zp[2*q+1], k0hi, a1);
      b0 = pkfma(zp[2*q],   k1lo, b0);
      b1 = pkfma(zp[2*q+1], k1hi, b1);
    }
    float s0 = (((a0.x+a0.y)+(a1.x+a1.y)) + d)*0.125f;
    float s1 = (((b0.x+b0.y)+(b1.x+b1.y)) + d)*0.125f;
    if (tid == m)   diag = s0;
    if (tid == m+1) diag = s1;
    S0 += __expf(s0);
    S1 += __expf(s1);
  }
  const float ann = __expf(diag) / (S0 + S1);

  // re-read own x row (LDS row intact), V proj + relu + residual, dense proj
  float o1[64];
  {
    float xr[64];
#pragma unroll
    for (int q=0;q<16;q++) {
      float4 v = *(const float4*)&ks[tid*68 + q*4];
      xr[q*4+0]=v.x; xr[q*4+1]=v.y; xr[q*4+2]=v.z; xr[q*4+3]=v.w;
    }
    v2f vacc[32];
#pragma unroll
    for (int j=0;j<32;j++) { v2f t; t.x = bv[2*j]; t.y = bv[2*j+1]; vacc[j] = t; }
    for (int i=0;i<64;i++) {
      v2f xv; xv.x = xr[i]; xv.y = xr[i];
      const float4* wr = (const float4*)(Wv + i*64);
#pragma unroll
      for (int q=0;q<16;q++) {
        float4 w4 = wr[q];
        v2f wlo; wlo.x=w4.x; wlo.y=w4.y;
        v2f whi; whi.x=w4.z; whi.y=w4.w;
        vacc[2*q]   = pkfma(xv, wlo, vacc[2*q]);
        vacc[2*q+1] = pkfma(xv, whi, vacc[2*q+1]);
      }
    }
#pragma unroll
    for (int o=0;o<64;o++) {
      float g = ann * ((o & 1) ? vacc[o>>1].y : vacc[o>>1].x);
      o1[o] = xr[o] + (g > 0.f ? g : 0.f);
    }
  }
  float dd[64];
  {
    v2f dacc[32];
#pragma unroll
    for (int j=0;j<32;j++) { v2f t; t.x = bd[2*j]; t.y = bd[2*j+1]; dacc[j] = t; }
    for (int i=0;i<64;i++) {
      v2f xv; xv.x = o1[i]; xv.y = o1[i];
      const float4* wr = (const float4*)(Wd + i*64);
#pragma unroll
      for (int q=0;q<16;q++) {
        float4 w4 = wr[q];
        v2f wlo; wlo.x=w4.x; wlo.y=w4.y;
        v2f whi; whi.x=w4.z; whi.y=w4.w;
        dacc[2*q]   = pkfma(xv, wlo, dacc[2*q]);
        dacc[2*q+1] = pkfma(xv, whi, dacc[2*q+1]);
      }
    }
#pragma unroll
    for (int o=0;o<64;o++) dd[o] = (o & 1) ? dacc[o>>1].y : dacc[o>>1].x;
  }
  float nrm = 0.f;
#pragma unroll
  for (int o=0;o<64;o++) nrm = fmaxf(nrm, fabsf(dd[o]));
  __syncthreads();                   // all score-phase reads of ks done before overwrite
#pragma unroll
  for (int q=0;q<16;q++) {
    float4 w;
    w.x = 0.5f*(dd[q*4+0]/nrm + 1.f);
    w.y = 0.5f*(dd[q*4+1]/nrm + 1.f);
    w.z = 0.5f*(dd[q*4+2]/nrm + 1.f);
    w.w = 0.5f*(dd[q*4+3]/nrm + 1.f);
    *(float4*)&ks[tid*68 + q*4] = w;
  }
  __syncthreads();
  float4* ob4 = (float4*)(vout + (size_t)bt*SLICE);
#pragma unroll
  for (int it=0;it<16;it++) {        // coalesced stage-out
    int flat4 = it*256 + tid;
    int n = flat4 >> 4, f4 = (flat4 & 15) << 2;
    ob4[flat4] = *(const float4*)&ks[n*68 + f4];
  }
}

// ---------------- radix-select histograms (values are non-negative floats) ----------------
template<int LEVEL>
__global__ __launch_bounds__(256) void hist_kernel(
    const float* __restrict__ v, unsigned* __restrict__ ghist,
    const unsigned* __restrict__ pfx)
{
  __shared__ unsigned h[4096];
  const int batch = blockIdx.x >> 5, chunk = blockIdx.x & 31;
  const int tid = threadIdx.x;
#pragma unroll
  for (int k=0;k<16;k++) h[k*256+tid] = 0u;
  __syncthreads();
  const unsigned p = pfx ? pfx[batch] : 0u;
  const float4* vb = (const float4*)(v + (size_t)batch*(TT*SLICE)) + chunk*8192 + tid;
  for (int k=0;k<32;k++) {
    float4 q = vb[k*256];
    float e[4] = {q.x,q.y,q.z,q.w};
#pragma unroll
    for (int j=0;j<4;j++) {
      unsigned u = __float_as_uint(e[j]);
      if (LEVEL==1) atomicAdd(&h[u>>20], 1u);
      else if ((u>>20)==p) atomicAdd(&h[(u>>8)&0xFFFu], 1u);
    }
  }
  __syncthreads();
  unsigned* gh = ghist + batch*4096;
#pragma unroll
  for (int k=0;k<16;k++) { unsigned c = h[k*256+tid]; if (c) atomicAdd(&gh[k*256+tid], c); }
}

__global__ __launch_bounds__(256) void hist8_kernel(
    const float* __restrict__ v, unsigned* __restrict__ ghist,
    const unsigned* __restrict__ pfx)
{
  __shared__ unsigned h[256];
  const int batch = blockIdx.x >> 5, chunk = blockIdx.x & 31;
  const int tid = threadIdx.x;
  h[tid] = 0u;
  __syncthreads();
  const unsigned p = pfx[batch];
  const float4* vb = (const float4*)(v + (size_t)batch*(TT*SLICE)) + chunk*8192 + tid;
  for (int k=0;k<32;k++) {
    float4 q = vb[k*256];
    float e[4] = {q.x,q.y,q.z,q.w};
#pragma unroll
    for (int j=0;j<4;j++) {
      unsigned u = __float_as_uint(e[j]);
      if ((u>>8)==p) atomicAdd(&h[u & 255u], 1u);
    }
  }
  __syncthreads();
  unsigned c = h[tid];
  if (c) atomicAdd(&ghist[batch*256+tid], c);
}

// ---------------- find bin containing the rank (block scan per batch) ----------------
template<int PER>
__global__ __launch_bounds__(256) void find_kernel(
    const unsigned* __restrict__ hist,
    const unsigned* __restrict__ rank_in, const unsigned* __restrict__ pfx_in,
    int pfx_shift, unsigned* __restrict__ pfx_out, unsigned* __restrict__ rank_out,
    float* __restrict__ mu, int final_level)
{
  __shared__ unsigned csum[256];
  const int batch = blockIdx.x;
  const int tid = threadIdx.x;
  const unsigned* hb = hist + batch*(PER*256);
  unsigned loc[PER];
  unsigned s = 0;
#pragma unroll
  for (int q=0;q<PER;q++) { loc[q] = hb[tid*PER+q]; s += loc[q]; }
  csum[tid] = s;
  __syncthreads();
  for (int off=1; off<256; off<<=1) {   // inclusive Hillis-Steele scan
    unsigned vv = csum[tid];
    unsigned ad = (tid >= off) ? csum[tid-off] : 0u;
    __syncthreads();
    csum[tid] = vv + ad;
    __syncthreads();
  }
  const unsigned rank = rank_in ? rank_in[batch] : RANK0;
  const unsigned excl = csum[tid] - s;
  if (rank >= excl && rank < excl + s) {
    unsigned r = rank - excl;
    int bin = 0;
#pragma unroll
    for (int q=0;q<PER;q++) {
      if (r < loc[q]) { bin = tid*PER + q; break; }
      r -= loc[q];
    }
    unsigned pf = pfx_in ? pfx_in[batch] : 0u;
    unsigned np = (pf << pfx_shift) | (unsigned)bin;
    if (final_level) { mu[batch] = __uint_as_float(np); }
    else { pfx_out[batch] = np; rank_out[batch] = r; }
  }
}

// ---------------- sigmoid + STE mask + predictor, per (b,t) ----------------
__global__ __launch_bounds__(256,2) void final_kernel(
    const float* __restrict__ v, const float* __restrict__ mu,
    const float* __restrict__ Wp, const float* __restrict__ bp,
    float* __restrict__ pred, float* __restrict__ mask)
{
  __shared__ float sl[NNODES*68];
  const int bt = blockIdx.x;
  const int b = bt >> 6;
  const int tid = threadIdx.x;
  const float4* vb4 = (const float4*)(v + (size_t)bt*SLICE);
#pragma unroll
  for (int it=0; it<16; it++) {
    int flat4 = it*256 + tid;
    int n = flat4 >> 4, f4 = (flat4 & 15) << 2;
    *(float4*)&sl[n*68 + f4] = vb4[flat4];
  }
  __syncthreads();
  const float muv = mu[b];
  float srow[64];                    // masked = s*mask row kept in registers
#pragma unroll
  for (int q=0;q<16;q++) {
    float4 vv = *(const float4*)&sl[tid*68 + q*4];
    float e0 = 1.f/(1.f + expf(-(vv.x - muv)));
    float e1 = 1.f/(1.f + expf(-(vv.y - muv)));
    float e2 = 1.f/(1.f + expf(-(vv.z - muv)));
    float e3 = 1.f/(1.f + expf(-(vv.w - muv)));
    float m0 = rintf(e0), m1 = rintf(e1), m2 = rintf(e2), m3 = rintf(e3);  // round half-even
    srow[q*4+0] = e0*m0; srow[q*4+1] = e1*m1; srow[q*4+2] = e2*m2; srow[q*4+3] = e3*m3;
    float4 w; w.x=m0; w.y=m1; w.z=m2; w.w=m3;
    *(float4*)&sl[tid*68 + q*4] = w;  // own row only: safe
  }
  __syncthreads();
  float4* mb4 = (float4*)(mask + (size_t)bt*SLICE);
#pragma unroll
  for (int it=0; it<16; it++) {
    int flat4 = it*256 + tid;
    int n = flat4 >> 4, f4 = (flat4 & 15) << 2;
    mb4[flat4] = *(const float4*)&sl[n*68 + f4];
  }
  // predictor row
  float acc[64];
#pragma unroll
  for (int o=0;o<64;o++) acc[o]=0.f;
  for (int i=0;i<64;i++) {
    float sv = srow[i];
#pragma unroll
    for (int o=0;o<64;o++) acc[o] = fmaf(sv, Wp[i*64+o], acc[o]);
  }
  __syncthreads();                   // mask stage-out finished reading sl
#pragma unroll
  for (int q=0;q<16;q++) {
    float4 w;
    w.x = acc[q*4+0]+bp[q*4+0]; w.y = acc[q*4+1]+bp[q*4+1];
    w.z = acc[q*4+2]+bp[q*4+2]; w.w = acc[q*4+3]+bp[q*4+3];
    *(float4*)&sl[tid*68 + q*4] = w;
  }
  __syncthreads();
  float4* pb4 = (float4*)(pred + (size_t)bt*SLICE);
#pragma unroll
  for (int it=0; it<16; it++) {
    int flat4 = it*256 + tid;
    int n = flat4 >> 4, f4 = (flat4 & 15) << 2;
    pb4[flat4] = *(const float4*)&sl[n*68 + f4];
  }
}

extern "C" void kernel_launch(void* const* d_in, const int* in_sizes, int n_in,
                              void* d_out, int out_size, void* d_ws, size_t ws_size,
                              hipStream_t stream) {
  const float* x   = (const float*)d_in[0];
  const float* Wc1 = (const float*)d_in[1];  const float* bc1 = (const float*)d_in[2];
  const float* Wc2 = (const float*)d_in[3];  const float* bc2 = (const float*)d_in[4];
  const float* Wc3 = (const float*)d_in[5];  const float* bc3 = (const float*)d_in[6];
  const float* Wq  = (const float*)d_in[7];  const float* bq  = (const float*)d_in[8];
  const float* Wk  = (const float*)d_in[9];  const float* bk  = (const float*)d_in[10];
  const float* Wv  = (const float*)d_in[11]; const float* bv  = (const float*)d_in[12];
  const float* Wd  = (const float*)d_in[13]; const float* bd  = (const float*)d_in[14];
  const float* Wp  = (const float*)d_in[15]; const float* bp  = (const float*)d_in[16];

  float* pred = (float*)d_out;       // also holds pre-sigmoid v, overwritten in place
  float* mask = pred + NTOT;         // also holds conv output x1, overwritten in place

  unsigned* hist1 = (unsigned*)d_ws;           // 32*4096
  unsigned* hist2 = hist1 + 32*4096;           // 32*4096
  unsigned* hist3 = hist2 + 32*4096;           // 32*256
  unsigned* pfx1  = hist3 + 32*256;
  unsigned* rank1 = pfx1 + 32;
  unsigned* pfx2  = rank1 + 32;
  unsigned* rank2 = pfx2 + 32;
  float*    muv   = (float*)(rank2 + 32);
  float*    Wcomb = muv + 32;                  // 7*64*64
  float*    bcomb = Wcomb + 7*64*64;           // 64
  float*    Wqk   = bcomb + 64;                // 64*64
  float*    zbv   = Wqk + 64*64;               // 64
  float*    wqbk  = zbv + 64;                  // 64
  float*    bqbk  = wqbk + 64;                 // 1

  hipMemsetAsync(d_ws, 0, (size_t)(32*4096*2 + 32*256)*sizeof(unsigned), stream);
  combine_w<<<112, 256, 0, stream>>>(Wc1,bc1,Wc2,bc2,Wc3,bc3,Wcomb,bcomb);
  combine_qk<<<17, 256, 0, stream>>>(Wq,bq,Wk,bk,Wqk,zbv,wqbk,bqbk);
  conv_kernel<<<BB*NNODES, 256, 0, stream>>>(x, Wcomb, bcomb, mask /*x1*/);
  attn_kernel<<<BB*TT, 256, 0, stream>>>(mask /*x1*/, Wqk,zbv,wqbk,bqbk, Wv,bv,Wd,bd, pred /*v*/);
  hist_kernel<1><<<1024, 256, 0, stream>>>(pred, hist1, nullptr);
  find_kernel<16><<<32, 256, 0, stream>>>(hist1, nullptr, nullptr, 0, pfx1, rank1, nullptr, 0);
  hist_kernel<2><<<1024, 256, 0, stream>>>(pred, hist2, pfx1);
  find_kernel<16><<<32, 256, 0, stream>>>(hist2, rank1, pfx1, 12, pfx2, rank2, nullptr, 0);
  hist8_kernel<<<1024, 256, 0, stream>>>(pred, hist3, pfx2);
  find_kernel<1><<<32, 256, 0, stream>>>(hist3, rank2, pfx2, 8, nullptr, nullptr, muv, 1);
  final_kernel<<<BB*TT, 256, 0, stream>>>(pred /*v*/, muv, Wp, bp, pred, mask);
}